// Round 4
// baseline (752.281 us; speedup 1.0000x reference)
//
#include <hip/hip_runtime.h>

// RETAIN forward. B=128 T=64 C=8000 H=256 D=16 G=768. All fp32 in/out;
// bf16 MFMA for matmuls, fp32 everywhere else.

typedef __attribute__((ext_vector_type(4))) float f32x4;
typedef __attribute__((ext_vector_type(8))) short short8;

__device__ inline short f2bf(float f) {
  unsigned u = __float_as_uint(f);
  u += 0x7fffu + ((u >> 16) & 1u);
  return (short)(u >> 16);
}
__device__ inline float sigf(float x) { return 1.f / (1.f + __expf(-x)); }
__device__ inline float tanh_fast(float x) {
  x = fminf(fmaxf(x, -15.f), 15.f);
  float e = __expf(2.f * x);
  return (e - 1.f) / (e + 1.f);
}

// ---------------- transpose embed_W [256,8000] -> Wt [8000,256] ----------------
__global__ void transpose_w(const float* __restrict__ in, float* __restrict__ outT) {
  __shared__ float tile[32][33];
  const int tx = threadIdx.x, ty = threadIdx.y;
  const int c0 = blockIdx.x * 32, h0 = blockIdx.y * 32;
#pragma unroll
  for (int k = 0; k < 4; ++k)
    tile[ty * 4 + k][tx] = in[(long)(h0 + ty * 4 + k) * 8000 + c0 + tx];
  __syncthreads();
#pragma unroll
  for (int k = 0; k < 4; ++k)
    outT[(long)(c0 + ty * 4 + k) * 256 + h0 + tx] = tile[tx][ty * 4 + k];
}

// ---------------- pad cls_W1/dl_W1 [256,272] -> [256,288] (zeros) ----------------
__global__ __launch_bounds__(256) void pad_w1(const float* __restrict__ w1,
                                              const float* __restrict__ w1d,
                                              float* __restrict__ o1,
                                              float* __restrict__ o2) {
  int idx = blockIdx.x * 256 + threadIdx.x;
  if (idx >= 2 * 256 * 288) return;
  int half = idx / (256 * 288);
  int r = idx % (256 * 288);
  int n = r / 288, k = r % 288;
  float v = (k < 272) ? (half ? w1d[n * 272 + k] : w1[n * 272 + k]) : 0.f;
  if (half) o2[r] = v; else o1[r] = v;
}

// ---------------- sparse embed: emb[bt,h] = b[h] + sum_c x!=0 * Wt[c,h] ----------------
__global__ __launch_bounds__(256) void embed_sparse(const float* __restrict__ x,
                                                    const float* __restrict__ Wt,
                                                    const float* __restrict__ eb,
                                                    float* __restrict__ emb) {
  __shared__ int sidx[512];
  __shared__ float sval[512];
  __shared__ int scnt;
  const int bt = blockIdx.x;  // 0..8191
  const int tid = threadIdx.x;
  if (tid == 0) scnt = 0;
  __syncthreads();
  const float* xr = x + (long)bt * 8000;
  for (int i = tid; i < 2000; i += 256) {
    float4 v = ((const float4*)xr)[i];
    if (v.x != 0.f) { int p = atomicAdd(&scnt, 1); if (p < 512) { sidx[p] = i * 4 + 0; sval[p] = v.x; } }
    if (v.y != 0.f) { int p = atomicAdd(&scnt, 1); if (p < 512) { sidx[p] = i * 4 + 1; sval[p] = v.y; } }
    if (v.z != 0.f) { int p = atomicAdd(&scnt, 1); if (p < 512) { sidx[p] = i * 4 + 2; sval[p] = v.z; } }
    if (v.w != 0.f) { int p = atomicAdd(&scnt, 1); if (p < 512) { sidx[p] = i * 4 + 3; sval[p] = v.w; } }
  }
  __syncthreads();
  const int n = min(scnt, 512);
  float acc = eb[tid];
  for (int i = 0; i < n; ++i) acc += sval[i] * Wt[(long)sidx[i] * 256 + tid];
  emb[(long)bt * 256 + tid] = acc;
}

// ---------------- generic GEMM: C[M,N] = act(A[M,K] @ B[N,K]^T + bias) ----------------
// bf16 MFMA 16x16x32, 64x64 tile, 4 waves. M,N mult of 64; K mult of 32.
__global__ __launch_bounds__(256) void gemm_bt(const float* __restrict__ A,
                                               const float* __restrict__ B,
                                               const float* __restrict__ bias,
                                               float* __restrict__ C,
                                               int M, int N, int K, int ldc, int act) {
  __shared__ short As[64][40];
  __shared__ short Bs[64][40];
  const int tid = threadIdx.x;
  const int lane = tid & 63, wave = tid >> 6;
  const int wm = wave >> 1, wn = wave & 1;
  const int l15 = lane & 15, lhi = lane >> 4;
  const int m0 = blockIdx.y * 64, n0 = blockIdx.x * 64;
  const int srow = tid >> 2, scol = (tid & 3) * 8;
  f32x4 acc[2][2];
#pragma unroll
  for (int i = 0; i < 2; ++i)
#pragma unroll
    for (int j = 0; j < 2; ++j) acc[i][j] = (f32x4){0.f, 0.f, 0.f, 0.f};

  for (int k0 = 0; k0 < K; k0 += 32) {
    __syncthreads();
    {
      const float* p = A + (long)(m0 + srow) * K + k0 + scol;
      float4 f0 = *(const float4*)p;
      float4 f1 = *(const float4*)(p + 4);
      short8 v;
      v[0] = f2bf(f0.x); v[1] = f2bf(f0.y); v[2] = f2bf(f0.z); v[3] = f2bf(f0.w);
      v[4] = f2bf(f1.x); v[5] = f2bf(f1.y); v[6] = f2bf(f1.z); v[7] = f2bf(f1.w);
      *(short8*)&As[srow][scol] = v;
      const float* q = B + (long)(n0 + srow) * K + k0 + scol;
      float4 g0 = *(const float4*)q;
      float4 g1 = *(const float4*)(q + 4);
      short8 u;
      u[0] = f2bf(g0.x); u[1] = f2bf(g0.y); u[2] = f2bf(g0.z); u[3] = f2bf(g0.w);
      u[4] = f2bf(g1.x); u[5] = f2bf(g1.y); u[6] = f2bf(g1.z); u[7] = f2bf(g1.w);
      *(short8*)&Bs[srow][scol] = u;
    }
    __syncthreads();
    short8 af0 = *(const short8*)&As[wm * 32 + l15][lhi * 8];
    short8 af1 = *(const short8*)&As[wm * 32 + 16 + l15][lhi * 8];
    short8 bf0 = *(const short8*)&Bs[wn * 32 + l15][lhi * 8];
    short8 bf1 = *(const short8*)&Bs[wn * 32 + 16 + l15][lhi * 8];
    acc[0][0] = __builtin_amdgcn_mfma_f32_16x16x32_bf16(af0, bf0, acc[0][0], 0, 0, 0);
    acc[0][1] = __builtin_amdgcn_mfma_f32_16x16x32_bf16(af0, bf1, acc[0][1], 0, 0, 0);
    acc[1][0] = __builtin_amdgcn_mfma_f32_16x16x32_bf16(af1, bf0, acc[1][0], 0, 0, 0);
    acc[1][1] = __builtin_amdgcn_mfma_f32_16x16x32_bf16(af1, bf1, acc[1][1], 0, 0, 0);
  }
#pragma unroll
  for (int j = 0; j < 2; ++j) {
    const int col = n0 + wn * 32 + j * 16 + l15;
    const float bv = bias[col];
#pragma unroll
    for (int i = 0; i < 2; ++i) {
#pragma unroll
      for (int r = 0; r < 4; ++r) {
        const int row = m0 + wm * 32 + i * 16 + lhi * 4 + r;
        float v = acc[i][j][r] + bv;
        if (act == 1) v = fmaxf(v, 0.f);
        else if (act == 2) v = tanh_fast(v);
        C[(long)row * ldc + col] = v;
      }
    }
  }
}

// ---------------- GRU scan ----------------
// block = (gru, chunk of 16 batches), 512 thr = 8 waves; wave w owns h-cols [w*32,w*32+32)
// v4: xp staged in LDS (single buffer, 48KB): loads for step t+1 issued into regs at
// top of step t (latency hides under MFMA+elementwise), ds_written after 2nd barrier.
// Single-buffered h in LDS (2 barriers/step). Weights wf register/AGPR-resident.
__global__ __launch_bounds__(512, 2)
void gru_scan(const float* __restrict__ xpa,
              const float* __restrict__ xpb,
              const float* __restrict__ aWhh,
              const float* __restrict__ bWhh,
              const float* __restrict__ abhh,
              const float* __restrict__ bbhh,
              float* __restrict__ aout,
              float* __restrict__ bout) {
  const int tid = threadIdx.x;
  const int lane = tid & 63, w = tid >> 6;
  const int l15 = lane & 15, lhi = lane >> 4;
  const int gru = blockIdx.x >> 3, chunk = blockIdx.x & 7;
  const int b0 = chunk * 16;
  const float* xp = gru ? xpb : xpa;
  const float* Whh = gru ? bWhh : aWhh;
  const float* bhh = gru ? bbhh : abhh;
  float* outp = gru ? bout : aout;

  // B-fragments of W_hh: wf[gate][s][kt]: lane holds W[g = e*256+w*32+s*16+l15, kt*32+lhi*8+j]
  short8 wf[3][2][8];
#pragma unroll
  for (int e = 0; e < 3; ++e) {
#pragma unroll
    for (int s = 0; s < 2; ++s) {
      const int g = e * 256 + w * 32 + s * 16 + l15;
#pragma unroll
      for (int kt = 0; kt < 8; ++kt) {
        const float* p = Whh + (long)g * 256 + kt * 32 + lhi * 8;
        float4 f0 = *(const float4*)p;
        float4 f1 = *(const float4*)(p + 4);
        short8 v;
        v[0] = f2bf(f0.x); v[1] = f2bf(f0.y); v[2] = f2bf(f0.z); v[3] = f2bf(f0.w);
        v[4] = f2bf(f1.x); v[5] = f2bf(f1.y); v[6] = f2bf(f1.z); v[7] = f2bf(f1.w);
        wf[e][s][kt] = v;
      }
    }
  }
  float bh[3][2];
#pragma unroll
  for (int e = 0; e < 3; ++e)
#pragma unroll
    for (int s = 0; s < 2; ++s)
      bh[e][s] = bhh[e * 256 + w * 32 + s * 16 + l15];

  __shared__ short hl[16][264];     // bf16 h (single buffer), padded stride
  __shared__ float xpl[16][776];    // fp32 xp slice for current step, padded stride
  for (int i = tid; i < 16 * 264; i += 512) (&hl[0][0])[i] = 0;

  // stage xp for t=0: thread loads 6 float4; f = i*512+tid -> row=f/192, c4=f%192
  {
#pragma unroll
    for (int i = 0; i < 6; ++i) {
      const int f = i * 512 + tid;
      const int row = f / 192, c4 = f % 192;
      const float4 v = *(const float4*)(xp + ((long)(b0 + row) * 64 + 0) * 768 + c4 * 4);
      *(float4*)&xpl[row][c4 * 4] = v;
    }
  }
  __syncthreads();

  float hreg[2][4];  // fp32 h state owned by this lane: [s][j] -> (b=lhi*4+j, col=w*32+s*16+l15)
#pragma unroll
  for (int s = 0; s < 2; ++s)
#pragma unroll
    for (int j = 0; j < 4; ++j) hreg[s][j] = 0.f;

  for (int t = 0; t < 64; ++t) {
    // phase 1: issue next step's xp loads into regs (fire-and-forget until phase 6)
    float4 xr[6];
    const int tn = (t + 1 < 64) ? t + 1 : 63;
#pragma unroll
    for (int i = 0; i < 6; ++i) {
      const int f = i * 512 + tid;
      const int row = f / 192, c4 = f % 192;
      xr[i] = *(const float4*)(xp + ((long)(b0 + row) * 64 + tn) * 768 + c4 * 4);
    }

    // phase 2: MFMA hp = h @ W^T over K=256
    f32x4 acc[3][2];
#pragma unroll
    for (int e = 0; e < 3; ++e)
#pragma unroll
      for (int s = 0; s < 2; ++s) acc[e][s] = (f32x4){0.f, 0.f, 0.f, 0.f};
#pragma unroll
    for (int kt = 0; kt < 8; ++kt) {
      short8 a = *(const short8*)&hl[l15][kt * 32 + lhi * 8];
#pragma unroll
      for (int e = 0; e < 3; ++e)
#pragma unroll
        for (int s = 0; s < 2; ++s)
          acc[e][s] = __builtin_amdgcn_mfma_f32_16x16x32_bf16(a, wf[e][s][kt], acc[e][s], 0, 0, 0);
    }
    __syncthreads();  // phase 3: all MFMA h-reads done before h overwritten

    // phase 4: elementwise GRU update; xp from LDS
#pragma unroll
    for (int s = 0; s < 2; ++s) {
      const int col = w * 32 + s * 16 + l15;
#pragma unroll
      for (int j = 0; j < 4; ++j) {
        const int bl = lhi * 4 + j;
        const float xvr = xpl[bl][col];
        const float xvz = xpl[bl][256 + col];
        const float xvn = xpl[bl][512 + col];
        const float r = sigf(xvr + acc[0][s][j] + bh[0][s]);
        const float z = sigf(xvz + acc[1][s][j] + bh[1][s]);
        const float n = tanh_fast(xvn + r * (acc[2][s][j] + bh[2][s]));
        const float hn = (1.f - z) * n + z * hreg[s][j];
        hreg[s][j] = hn;
        hl[bl][col] = f2bf(hn);
        outp[((long)(b0 + bl) * 64 + t) * 256 + col] = hn;
      }
    }
    __syncthreads();  // phase 5: xp reads done before overwrite

    // phase 6: write staged xp (t+1) into LDS
#pragma unroll
    for (int i = 0; i < 6; ++i) {
      const int f = i * 512 + tid;
      const int row = f / 192, c4 = f % 192;
      *(float4*)&xpl[row][c4 * 4] = xr[i];
    }
    // next iteration's phase-3 barrier is NOT between phase 6 writes and phase 2'
    // MFMA reads -- but phase 2' only reads hl (untouched here); phase 4' reads
    // xpl after the phase-3' barrier. Safe with 2 barriers/step... except phase 2'
    // ds-reads race phase 6 ds-writes only on different regions. OK.
  }
}

// ---------------- e_alpha + softmax over T ----------------
__global__ __launch_bounds__(256) void alpha_softmax(const float* __restrict__ aout,
                                                     const float* __restrict__ aW,
                                                     const float* __restrict__ ab,
                                                     float* __restrict__ alpha) {
  __shared__ float part[64][4];
  const int b = blockIdx.x, tid = threadIdx.x;
  const int t = tid >> 2, q = tid & 3;
  const float* p = aout + (long)(b * 64 + t) * 256 + q * 64;
  const float* wv = aW + q * 64;
  float s = 0.f;
  for (int i = 0; i < 64; ++i) s += p[i] * wv[i];
  part[t][q] = s;
  __syncthreads();
  if (tid < 64) {
    float e = part[tid][0] + part[tid][1] + part[tid][2] + part[tid][3] + ab[0];
    float m = e;
    for (int k = 32; k; k >>= 1) m = fmaxf(m, __shfl_xor(m, k));
    float ex = __expf(e - m);
    float sum = ex;
    for (int k = 32; k; k >>= 1) sum += __shfl_xor(sum, k);
    alpha[b * 64 + tid] = ex / sum;
  }
}

// ---------------- context + combined[B,288] (context|demo|zero-pad) ----------------
__global__ __launch_bounds__(256) void context_combined(const float* __restrict__ alpha,
                                                        const float* __restrict__ emb,
                                                        const float* __restrict__ beta,
                                                        const float* __restrict__ demo,
                                                        float* __restrict__ comb) {
  const int b = blockIdx.x, h = threadIdx.x;
  float acc = 0.f;
  for (int t = 0; t < 64; ++t) {
    const float a = alpha[b * 64 + t];
    const long ix = (long)(b * 64 + t) * 256 + h;
    acc += a * emb[ix] * beta[ix];
  }
  comb[b * 288 + h] = acc;
  if (h < 16) comb[b * 288 + 256 + h] = demo[b * 16 + h];
  else if (h < 32) comb[b * 288 + 256 + h] = 0.f;
}

// ---------------- death/LOS head final dot ----------------
__global__ __launch_bounds__(64) void dl_head(const float* __restrict__ h2,
                                              const float* __restrict__ w,
                                              const float* __restrict__ bias,
                                              float* __restrict__ out) {
  const int b = blockIdx.x, lane = threadIdx.x;
  float s = 0.f;
#pragma unroll
  for (int i = 0; i < 4; ++i) s += h2[b * 256 + lane * 4 + i] * w[lane * 4 + i];
  for (int k = 32; k; k >>= 1) s += __shfl_xor(s, k);
  if (lane == 0) out[(long)b * 8001 + 8000] = s + bias[0];
}

extern "C" void kernel_launch(void* const* d_in, const int* in_sizes, int n_in,
                              void* d_out, int out_size, void* d_ws, size_t ws_size,
                              hipStream_t stream) {
  (void)in_sizes; (void)n_in; (void)out_size; (void)ws_size;
  const float* x      = (const float*)d_in[0];
  const float* demo   = (const float*)d_in[1];
  const float* embW   = (const float*)d_in[2];
  const float* embB   = (const float*)d_in[3];
  const float* aWih   = (const float*)d_in[4];
  const float* aWhh   = (const float*)d_in[5];
  const float* abih   = (const float*)d_in[6];
  const float* abhh   = (const float*)d_in[7];
  const float* bWih   = (const float*)d_in[8];
  const float* bWhh   = (const float*)d_in[9];
  const float* bbih   = (const float*)d_in[10];
  const float* bbhh   = (const float*)d_in[11];
  const float* attnAW = (const float*)d_in[12];
  const float* attnAb = (const float*)d_in[13];
  const float* attnBW = (const float*)d_in[14];
  const float* attnBb = (const float*)d_in[15];
  const float* clsW1  = (const float*)d_in[16];
  const float* clsb1  = (const float*)d_in[17];
  const float* clsW2  = (const float*)d_in[18];
  const float* clsb2  = (const float*)d_in[19];
  const float* dlW1   = (const float*)d_in[20];
  const float* dlb1   = (const float*)d_in[21];
  const float* dlW2   = (const float*)d_in[22];
  const float* dlb2   = (const float*)d_in[23];
  float* out = (float*)d_out;
  float* ws = (float*)d_ws;

  float* Wt    = ws;               // 8000*256     = 2,048,000
  float* emb   = Wt + 2048000;     // 8192*256     = 2,097,152
  float* xpa   = emb + 2097152;    // 8192*768     = 6,291,456
  float* xpb   = xpa + 6291456;    // 6,291,456
  float* aoutB = xpb + 6291456;    // 2,097,152
  float* boutB = aoutB + 2097152;  // 2,097,152
  float* betaB = boutB + 2097152;  // 2,097,152
  float* alpha = betaB + 2097152;  // 8,192
  float* comb  = alpha + 8192;     // 128*288 = 36,864
  float* h1    = comb + 36864;     // 32,768
  float* h2    = h1 + 32768;       // 32,768
  float* W1p   = h2 + 32768;       // 73,728
  float* W1pd  = W1p + 73728;      // 73,728  (total ~93.1 MB)

  transpose_w<<<dim3(250, 8), dim3(32, 8), 0, stream>>>(embW, Wt);
  pad_w1<<<dim3(576), dim3(256), 0, stream>>>(clsW1, dlW1, W1p, W1pd);
  embed_sparse<<<dim3(8192), dim3(256), 0, stream>>>(x, Wt, embB, emb);
  gemm_bt<<<dim3(12, 128), dim3(256), 0, stream>>>(emb, aWih, abih, xpa, 8192, 768, 256, 768, 0);
  gemm_bt<<<dim3(12, 128), dim3(256), 0, stream>>>(emb, bWih, bbih, xpb, 8192, 768, 256, 768, 0);
  gru_scan<<<dim3(16), dim3(512), 0, stream>>>(xpa, xpb, aWhh, bWhh, abhh, bbhh, aoutB, boutB);
  alpha_softmax<<<dim3(128), dim3(256), 0, stream>>>(aoutB, attnAW, attnAb, alpha);
  gemm_bt<<<dim3(4, 128), dim3(256), 0, stream>>>(boutB, attnBW, attnBb, betaB, 8192, 256, 256, 256, 2);
  context_combined<<<dim3(128), dim3(256), 0, stream>>>(alpha, emb, betaB, demo, comb);
  gemm_bt<<<dim3(4, 2), dim3(256), 0, stream>>>(comb, W1p, clsb1, h1, 128, 256, 288, 256, 1);
  gemm_bt<<<dim3(4, 2), dim3(256), 0, stream>>>(comb, W1pd, dlb1, h2, 128, 256, 288, 256, 1);
  gemm_bt<<<dim3(125, 2), dim3(256), 0, stream>>>(h1, clsW2, clsb2, out, 128, 8000, 256, 8001, 0);
  dl_head<<<dim3(128), dim3(64), 0, stream>>>(h2, dlW2, dlb2, out);
}

// Round 5
// 571.517 us; speedup vs baseline: 1.3163x; 1.3163x over previous
//
#include <hip/hip_runtime.h>

// RETAIN forward. B=128 T=64 C=8000 H=256 D=16 G=768. All fp32 in/out;
// bf16 MFMA for matmuls, fp32 everywhere else.

typedef __attribute__((ext_vector_type(4))) float f32x4;
typedef __attribute__((ext_vector_type(8))) short short8;

__device__ inline short f2bf(float f) {
  unsigned u = __float_as_uint(f);
  u += 0x7fffu + ((u >> 16) & 1u);
  return (short)(u >> 16);
}
__device__ inline float sigf(float x) { return 1.f / (1.f + __expf(-x)); }
__device__ inline float tanh_fast(float x) {
  x = fminf(fmaxf(x, -15.f), 15.f);
  float e = __expf(2.f * x);
  return (e - 1.f) / (e + 1.f);
}

// ---------------- transpose embed_W [256,8000] -> Wt [8000,256] ----------------
__global__ void transpose_w(const float* __restrict__ in, float* __restrict__ outT) {
  __shared__ float tile[32][33];
  const int tx = threadIdx.x, ty = threadIdx.y;
  const int c0 = blockIdx.x * 32, h0 = blockIdx.y * 32;
#pragma unroll
  for (int k = 0; k < 4; ++k)
    tile[ty * 4 + k][tx] = in[(long)(h0 + ty * 4 + k) * 8000 + c0 + tx];
  __syncthreads();
#pragma unroll
  for (int k = 0; k < 4; ++k)
    outT[(long)(c0 + ty * 4 + k) * 256 + h0 + tx] = tile[tx][ty * 4 + k];
}

// ---------------- pad cls_W1/dl_W1 [256,272] -> [256,288] (zeros) ----------------
__global__ __launch_bounds__(256) void pad_w1(const float* __restrict__ w1,
                                              const float* __restrict__ w1d,
                                              float* __restrict__ o1,
                                              float* __restrict__ o2) {
  int idx = blockIdx.x * 256 + threadIdx.x;
  if (idx >= 2 * 256 * 288) return;
  int half = idx / (256 * 288);
  int r = idx % (256 * 288);
  int n = r / 288, k = r % 288;
  float v = (k < 272) ? (half ? w1d[n * 272 + k] : w1[n * 272 + k]) : 0.f;
  if (half) o2[r] = v; else o1[r] = v;
}

// ---------------- sparse embed: emb[bt,h] = b[h] + sum_c x!=0 * Wt[c,h] ----------------
__global__ __launch_bounds__(256) void embed_sparse(const float* __restrict__ x,
                                                    const float* __restrict__ Wt,
                                                    const float* __restrict__ eb,
                                                    float* __restrict__ emb) {
  __shared__ int sidx[512];
  __shared__ float sval[512];
  __shared__ int scnt;
  const int bt = blockIdx.x;  // 0..8191
  const int tid = threadIdx.x;
  if (tid == 0) scnt = 0;
  __syncthreads();
  const float* xr = x + (long)bt * 8000;
  for (int i = tid; i < 2000; i += 256) {
    float4 v = ((const float4*)xr)[i];
    if (v.x != 0.f) { int p = atomicAdd(&scnt, 1); if (p < 512) { sidx[p] = i * 4 + 0; sval[p] = v.x; } }
    if (v.y != 0.f) { int p = atomicAdd(&scnt, 1); if (p < 512) { sidx[p] = i * 4 + 1; sval[p] = v.y; } }
    if (v.z != 0.f) { int p = atomicAdd(&scnt, 1); if (p < 512) { sidx[p] = i * 4 + 2; sval[p] = v.z; } }
    if (v.w != 0.f) { int p = atomicAdd(&scnt, 1); if (p < 512) { sidx[p] = i * 4 + 3; sval[p] = v.w; } }
  }
  __syncthreads();
  const int n = min(scnt, 512);
  float acc = eb[tid];
  for (int i = 0; i < n; ++i) acc += sval[i] * Wt[(long)sidx[i] * 256 + tid];
  emb[(long)bt * 256 + tid] = acc;
}

// ---------------- generic GEMM: C[M,N] = act(A[M,K] @ B[N,K]^T + bias) ----------------
// bf16 MFMA 16x16x32, 64x64 tile, 4 waves. M,N mult of 64; K mult of 32.
__global__ __launch_bounds__(256) void gemm_bt(const float* __restrict__ A,
                                               const float* __restrict__ B,
                                               const float* __restrict__ bias,
                                               float* __restrict__ C,
                                               int M, int N, int K, int ldc, int act) {
  __shared__ short As[64][40];
  __shared__ short Bs[64][40];
  const int tid = threadIdx.x;
  const int lane = tid & 63, wave = tid >> 6;
  const int wm = wave >> 1, wn = wave & 1;
  const int l15 = lane & 15, lhi = lane >> 4;
  const int m0 = blockIdx.y * 64, n0 = blockIdx.x * 64;
  const int srow = tid >> 2, scol = (tid & 3) * 8;
  f32x4 acc[2][2];
#pragma unroll
  for (int i = 0; i < 2; ++i)
#pragma unroll
    for (int j = 0; j < 2; ++j) acc[i][j] = (f32x4){0.f, 0.f, 0.f, 0.f};

  for (int k0 = 0; k0 < K; k0 += 32) {
    __syncthreads();
    {
      const float* p = A + (long)(m0 + srow) * K + k0 + scol;
      float4 f0 = *(const float4*)p;
      float4 f1 = *(const float4*)(p + 4);
      short8 v;
      v[0] = f2bf(f0.x); v[1] = f2bf(f0.y); v[2] = f2bf(f0.z); v[3] = f2bf(f0.w);
      v[4] = f2bf(f1.x); v[5] = f2bf(f1.y); v[6] = f2bf(f1.z); v[7] = f2bf(f1.w);
      *(short8*)&As[srow][scol] = v;
      const float* q = B + (long)(n0 + srow) * K + k0 + scol;
      float4 g0 = *(const float4*)q;
      float4 g1 = *(const float4*)(q + 4);
      short8 u;
      u[0] = f2bf(g0.x); u[1] = f2bf(g0.y); u[2] = f2bf(g0.z); u[3] = f2bf(g0.w);
      u[4] = f2bf(g1.x); u[5] = f2bf(g1.y); u[6] = f2bf(g1.z); u[7] = f2bf(g1.w);
      *(short8*)&Bs[srow][scol] = u;
    }
    __syncthreads();
    short8 af0 = *(const short8*)&As[wm * 32 + l15][lhi * 8];
    short8 af1 = *(const short8*)&As[wm * 32 + 16 + l15][lhi * 8];
    short8 bf0 = *(const short8*)&Bs[wn * 32 + l15][lhi * 8];
    short8 bf1 = *(const short8*)&Bs[wn * 32 + 16 + l15][lhi * 8];
    acc[0][0] = __builtin_amdgcn_mfma_f32_16x16x32_bf16(af0, bf0, acc[0][0], 0, 0, 0);
    acc[0][1] = __builtin_amdgcn_mfma_f32_16x16x32_bf16(af0, bf1, acc[0][1], 0, 0, 0);
    acc[1][0] = __builtin_amdgcn_mfma_f32_16x16x32_bf16(af1, bf0, acc[1][0], 0, 0, 0);
    acc[1][1] = __builtin_amdgcn_mfma_f32_16x16x32_bf16(af1, bf1, acc[1][1], 0, 0, 0);
  }
#pragma unroll
  for (int j = 0; j < 2; ++j) {
    const int col = n0 + wn * 32 + j * 16 + l15;
    const float bv = bias[col];
#pragma unroll
    for (int i = 0; i < 2; ++i) {
#pragma unroll
      for (int r = 0; r < 4; ++r) {
        const int row = m0 + wm * 32 + i * 16 + lhi * 4 + r;
        float v = acc[i][j][r] + bv;
        if (act == 1) v = fmaxf(v, 0.f);
        else if (act == 2) v = tanh_fast(v);
        C[(long)row * ldc + col] = v;
      }
    }
  }
}

// ---------------- GRU scan v5 ----------------
// block = (gru, chunk of 16 batches), 512 thr = 8 waves; wave w owns h-cols [w*32,w*32+32).
// Weights: kt 0..6 slices FORCED into AGPRs via inline-asm MFMA "a" constraints
// (compiler refuses >128 arch VGPRs; R1-R4 were all scratch-spill-bound). kt=7
// slice lives in LDS. xp staged via global_load_lds, double-buffered, counted
// vmcnt(6) + raw s_barrier (no vmcnt(0) drain in loop).
#define MFMA_AA(ACC, AF, BF) \
  asm volatile("v_mfma_f32_16x16x32_bf16 %0, %1, %2, %0" : "+a"(ACC) : "v"(AF), "a"(BF))
#define MFMA_AV(ACC, AF, BF) \
  asm volatile("v_mfma_f32_16x16x32_bf16 %0, %1, %2, %0" : "+a"(ACC) : "v"(AF), "v"(BF))

__global__ __launch_bounds__(512, 2)
void gru_scan(const float* __restrict__ xpa,
              const float* __restrict__ xpb,
              const float* __restrict__ aWhh,
              const float* __restrict__ bWhh,
              const float* __restrict__ abhh,
              const float* __restrict__ bbhh,
              float* __restrict__ aout,
              float* __restrict__ bout) {
  const int tid = threadIdx.x;
  const int lane = tid & 63, w = tid >> 6;
  const int l15 = lane & 15, lhi = lane >> 4;
  const int gru = blockIdx.x >> 3, chunk = blockIdx.x & 7;
  const int b0 = chunk * 16;
  const float* xp = gru ? xpb : xpa;
  const float* Whh = gru ? bWhh : aWhh;
  const float* bhh = gru ? bbhh : abhh;
  float* outp = gru ? bout : aout;

  __shared__ short hl[16][264];         // bf16 h, single buffer, padded stride
  __shared__ float xpl[2][16][768];     // xp slices, double buffer (gld target: linear)
  __shared__ short wlds[8][6][64][8];   // kt=7 weight slice fragments [w][e*2+s][lane]

  // weights kt 0..6 -> AGPR-bound fragments
  short8 wf[3][2][7];
#pragma unroll
  for (int e = 0; e < 3; ++e) {
#pragma unroll
    for (int s = 0; s < 2; ++s) {
      const int g = e * 256 + w * 32 + s * 16 + l15;
#pragma unroll
      for (int kt = 0; kt < 7; ++kt) {
        const float* p = Whh + (long)g * 256 + kt * 32 + lhi * 8;
        float4 f0 = *(const float4*)p;
        float4 f1 = *(const float4*)(p + 4);
        short8 v;
        v[0] = f2bf(f0.x); v[1] = f2bf(f0.y); v[2] = f2bf(f0.z); v[3] = f2bf(f0.w);
        v[4] = f2bf(f1.x); v[5] = f2bf(f1.y); v[6] = f2bf(f1.z); v[7] = f2bf(f1.w);
        wf[e][s][kt] = v;
      }
      // kt = 7 slice -> LDS
      {
        const float* p = Whh + (long)g * 256 + 224 + lhi * 8;
        float4 f0 = *(const float4*)p;
        float4 f1 = *(const float4*)(p + 4);
        short8 v;
        v[0] = f2bf(f0.x); v[1] = f2bf(f0.y); v[2] = f2bf(f0.z); v[3] = f2bf(f0.w);
        v[4] = f2bf(f1.x); v[5] = f2bf(f1.y); v[6] = f2bf(f1.z); v[7] = f2bf(f1.w);
        *(short8*)&wlds[w][e * 2 + s][lane][0] = v;
      }
    }
  }
  float bh[3][2];
#pragma unroll
  for (int e = 0; e < 3; ++e)
#pragma unroll
    for (int s = 0; s < 2; ++s)
      bh[e][s] = bhh[e * 256 + w * 32 + s * 16 + l15];

  for (int i = tid; i < 16 * 264; i += 512) (&hl[0][0])[i] = 0;

  // stage xp[t=0] -> buffer 0 (6 gld calls/wave: rows w*2, w*2+1, 3 segs of 256 floats)
#pragma unroll
  for (int k = 0; k < 6; ++k) {
    const int row = (w << 1) + (k / 3);
    const int seg = k % 3;
    const float* gp = xp + ((long)((b0 + row) * 64 + 0) * 768) + seg * 256 + lane * 4;
    __builtin_amdgcn_global_load_lds((const __attribute__((address_space(1))) unsigned int*)gp,
                                     (__attribute__((address_space(3))) unsigned int*)&xpl[0][row][seg * 256],
                                     16, 0, 0);
  }
  asm volatile("s_waitcnt vmcnt(0)" ::: "memory");
  __syncthreads();

  float hreg[2][4];  // fp32 h state: [s][j] -> (b=lhi*4+j, col=w*32+s*16+l15)
#pragma unroll
  for (int s = 0; s < 2; ++s)
#pragma unroll
    for (int j = 0; j < 4; ++j) hreg[s][j] = 0.f;

  for (int t = 0; t < 64; ++t) {
    const int cur = t & 1, nb = cur ^ 1;
    const int tn = (t + 1 < 64) ? t + 1 : 63;

    // phase 1: issue next step's xp loads (async -> xpl[nb])
#pragma unroll
    for (int k = 0; k < 6; ++k) {
      const int row = (w << 1) + (k / 3);
      const int seg = k % 3;
      const float* gp = xp + ((long)((b0 + row) * 64 + tn) * 768) + seg * 256 + lane * 4;
      __builtin_amdgcn_global_load_lds((const __attribute__((address_space(1))) unsigned int*)gp,
                                       (__attribute__((address_space(3))) unsigned int*)&xpl[nb][row][seg * 256],
                                       16, 0, 0);
    }

    // phase 2: hp = h @ W^T (AGPR weights kt 0..6, LDS weights kt 7)
    f32x4 acc[3][2];
#pragma unroll
    for (int e = 0; e < 3; ++e)
#pragma unroll
      for (int s = 0; s < 2; ++s) acc[e][s] = (f32x4){0.f, 0.f, 0.f, 0.f};
    asm volatile("s_nop 3");  // accvgpr_write(acc zeros) -> mfma read-C hazard
#pragma unroll
    for (int kt = 0; kt < 7; ++kt) {
      short8 a = *(const short8*)&hl[l15][kt * 32 + lhi * 8];
      MFMA_AA(acc[0][0], a, wf[0][0][kt]);
      MFMA_AA(acc[0][1], a, wf[0][1][kt]);
      MFMA_AA(acc[1][0], a, wf[1][0][kt]);
      MFMA_AA(acc[1][1], a, wf[1][1][kt]);
      MFMA_AA(acc[2][0], a, wf[2][0][kt]);
      MFMA_AA(acc[2][1], a, wf[2][1][kt]);
    }
    {
      short8 a = *(const short8*)&hl[l15][224 + lhi * 8];
#pragma unroll
      for (int e = 0; e < 3; ++e)
#pragma unroll
        for (int s = 0; s < 2; ++s) {
          short8 wl = *(const short8*)&wlds[w][e * 2 + s][lane][0];
          MFMA_AV(acc[e][s], a, wl);
        }
    }
    asm volatile("s_nop 7\n\ts_nop 7");  // mfma write -> VALU accvgpr_read hazard

    // barrier 1: xpl[cur] loads retired everywhere (6 newest = this step's issues)
    asm volatile("s_waitcnt vmcnt(6)" ::: "memory");
    __builtin_amdgcn_s_barrier();
    __builtin_amdgcn_sched_barrier(0);

    // phase 4: elementwise GRU update; xp from LDS
#pragma unroll
    for (int s = 0; s < 2; ++s) {
      const int col = w * 32 + s * 16 + l15;
#pragma unroll
      for (int j = 0; j < 4; ++j) {
        const int bl = lhi * 4 + j;
        const float xvr = xpl[cur][bl][col];
        const float xvz = xpl[cur][bl][256 + col];
        const float xvn = xpl[cur][bl][512 + col];
        const float r = sigf(xvr + acc[0][s][j] + bh[0][s]);
        const float z = sigf(xvz + acc[1][s][j] + bh[1][s]);
        const float n = tanh_fast(xvn + r * (acc[2][s][j] + bh[2][s]));
        const float hn = (1.f - z) * n + z * hreg[s][j];
        hreg[s][j] = hn;
        hl[bl][col] = f2bf(hn);
        outp[((long)(b0 + bl) * 64 + t) * 256 + col] = hn;
      }
    }

    // barrier 2: h writes visible; xpl[cur] reads done before next overwrite
    asm volatile("s_waitcnt lgkmcnt(0)" ::: "memory");
    __builtin_amdgcn_sched_barrier(0);
    __builtin_amdgcn_s_barrier();
    __builtin_amdgcn_sched_barrier(0);
  }
}

// ---------------- e_alpha + softmax over T ----------------
__global__ __launch_bounds__(256) void alpha_softmax(const float* __restrict__ aout,
                                                     const float* __restrict__ aW,
                                                     const float* __restrict__ ab,
                                                     float* __restrict__ alpha) {
  __shared__ float part[64][4];
  const int b = blockIdx.x, tid = threadIdx.x;
  const int t = tid >> 2, q = tid & 3;
  const float* p = aout + (long)(b * 64 + t) * 256 + q * 64;
  const float* wv = aW + q * 64;
  float s = 0.f;
  for (int i = 0; i < 64; ++i) s += p[i] * wv[i];
  part[t][q] = s;
  __syncthreads();
  if (tid < 64) {
    float e = part[tid][0] + part[tid][1] + part[tid][2] + part[tid][3] + ab[0];
    float m = e;
    for (int k = 32; k; k >>= 1) m = fmaxf(m, __shfl_xor(m, k));
    float ex = __expf(e - m);
    float sum = ex;
    for (int k = 32; k; k >>= 1) sum += __shfl_xor(sum, k);
    alpha[b * 64 + tid] = ex / sum;
  }
}

// ---------------- context + combined[B,288] (context|demo|zero-pad) ----------------
__global__ __launch_bounds__(256) void context_combined(const float* __restrict__ alpha,
                                                        const float* __restrict__ emb,
                                                        const float* __restrict__ beta,
                                                        const float* __restrict__ demo,
                                                        float* __restrict__ comb) {
  const int b = blockIdx.x, h = threadIdx.x;
  float acc = 0.f;
  for (int t = 0; t < 64; ++t) {
    const float a = alpha[b * 64 + t];
    const long ix = (long)(b * 64 + t) * 256 + h;
    acc += a * emb[ix] * beta[ix];
  }
  comb[b * 288 + h] = acc;
  if (h < 16) comb[b * 288 + 256 + h] = demo[b * 16 + h];
  else if (h < 32) comb[b * 288 + 256 + h] = 0.f;
}

// ---------------- death/LOS head final dot ----------------
__global__ __launch_bounds__(64) void dl_head(const float* __restrict__ h2,
                                              const float* __restrict__ w,
                                              const float* __restrict__ bias,
                                              float* __restrict__ out) {
  const int b = blockIdx.x, lane = threadIdx.x;
  float s = 0.f;
#pragma unroll
  for (int i = 0; i < 4; ++i) s += h2[b * 256 + lane * 4 + i] * w[lane * 4 + i];
  for (int k = 32; k; k >>= 1) s += __shfl_xor(s, k);
  if (lane == 0) out[(long)b * 8001 + 8000] = s + bias[0];
}

extern "C" void kernel_launch(void* const* d_in, const int* in_sizes, int n_in,
                              void* d_out, int out_size, void* d_ws, size_t ws_size,
                              hipStream_t stream) {
  (void)in_sizes; (void)n_in; (void)out_size; (void)ws_size;
  const float* x      = (const float*)d_in[0];
  const float* demo   = (const float*)d_in[1];
  const float* embW   = (const float*)d_in[2];
  const float* embB   = (const float*)d_in[3];
  const float* aWih   = (const float*)d_in[4];
  const float* aWhh   = (const float*)d_in[5];
  const float* abih   = (const float*)d_in[6];
  const float* abhh   = (const float*)d_in[7];
  const float* bWih   = (const float*)d_in[8];
  const float* bWhh   = (const float*)d_in[9];
  const float* bbih   = (const float*)d_in[10];
  const float* bbhh   = (const float*)d_in[11];
  const float* attnAW = (const float*)d_in[12];
  const float* attnAb = (const float*)d_in[13];
  const float* attnBW = (const float*)d_in[14];
  const float* attnBb = (const float*)d_in[15];
  const float* clsW1  = (const float*)d_in[16];
  const float* clsb1  = (const float*)d_in[17];
  const float* clsW2  = (const float*)d_in[18];
  const float* clsb2  = (const float*)d_in[19];
  const float* dlW1   = (const float*)d_in[20];
  const float* dlb1   = (const float*)d_in[21];
  const float* dlW2   = (const float*)d_in[22];
  const float* dlb2   = (const float*)d_in[23];
  float* out = (float*)d_out;
  float* ws = (float*)d_ws;

  float* Wt    = ws;               // 8000*256     = 2,048,000
  float* emb   = Wt + 2048000;     // 8192*256     = 2,097,152
  float* xpa   = emb + 2097152;    // 8192*768     = 6,291,456
  float* xpb   = xpa + 6291456;    // 6,291,456
  float* aoutB = xpb + 6291456;    // 2,097,152
  float* boutB = aoutB + 2097152;  // 2,097,152
  float* betaB = boutB + 2097152;  // 2,097,152
  float* alpha = betaB + 2097152;  // 8,192
  float* comb  = alpha + 8192;     // 128*288 = 36,864
  float* h1    = comb + 36864;     // 32,768
  float* h2    = h1 + 32768;       // 32,768
  float* W1p   = h2 + 32768;       // 73,728
  float* W1pd  = W1p + 73728;      // 73,728  (total ~93.1 MB)

  transpose_w<<<dim3(250, 8), dim3(32, 8), 0, stream>>>(embW, Wt);
  pad_w1<<<dim3(576), dim3(256), 0, stream>>>(clsW1, dlW1, W1p, W1pd);
  embed_sparse<<<dim3(8192), dim3(256), 0, stream>>>(x, Wt, embB, emb);
  gemm_bt<<<dim3(12, 128), dim3(256), 0, stream>>>(emb, aWih, abih, xpa, 8192, 768, 256, 768, 0);
  gemm_bt<<<dim3(12, 128), dim3(256), 0, stream>>>(emb, bWih, bbih, xpb, 8192, 768, 256, 768, 0);
  gru_scan<<<dim3(16), dim3(512), 0, stream>>>(xpa, xpb, aWhh, bWhh, abhh, bbhh, aoutB, boutB);
  alpha_softmax<<<dim3(128), dim3(256), 0, stream>>>(aoutB, attnAW, attnAb, alpha);
  gemm_bt<<<dim3(4, 128), dim3(256), 0, stream>>>(boutB, attnBW, attnBb, betaB, 8192, 256, 256, 256, 2);
  context_combined<<<dim3(128), dim3(256), 0, stream>>>(alpha, emb, betaB, demo, comb);
  gemm_bt<<<dim3(4, 2), dim3(256), 0, stream>>>(comb, W1p, clsb1, h1, 128, 256, 288, 256, 1);
  gemm_bt<<<dim3(4, 2), dim3(256), 0, stream>>>(comb, W1pd, dlb1, h2, 128, 256, 288, 256, 1);
  gemm_bt<<<dim3(125, 2), dim3(256), 0, stream>>>(h1, clsW2, clsb2, out, 128, 8000, 256, 8001, 0);
  dl_head<<<dim3(128), dim3(64), 0, stream>>>(h2, dlW2, dlb2, out);
}

// Round 6
// 416.225 us; speedup vs baseline: 1.8074x; 1.3731x over previous
//
#include <hip/hip_runtime.h>

// RETAIN forward. B=128 T=64 C=8000 H=256 D=16 G=768. All fp32 in/out;
// bf16 MFMA for matmuls, fp32 everywhere else.

typedef __attribute__((ext_vector_type(4))) float f32x4;
typedef __attribute__((ext_vector_type(8))) short short8;

__device__ inline short f2bf(float f) {
  unsigned u = __float_as_uint(f);
  u += 0x7fffu + ((u >> 16) & 1u);
  return (short)(u >> 16);
}
__device__ inline float sigf(float x) { return 1.f / (1.f + __expf(-x)); }
__device__ inline float tanh_fast(float x) {
  x = fminf(fmaxf(x, -15.f), 15.f);
  float e = __expf(2.f * x);
  return (e - 1.f) / (e + 1.f);
}

// ---------------- transpose embed_W [256,8000] -> Wt [8000,256] ----------------
__global__ void transpose_w(const float* __restrict__ in, float* __restrict__ outT) {
  __shared__ float tile[32][33];
  const int tx = threadIdx.x, ty = threadIdx.y;
  const int c0 = blockIdx.x * 32, h0 = blockIdx.y * 32;
#pragma unroll
  for (int k = 0; k < 4; ++k)
    tile[ty * 4 + k][tx] = in[(long)(h0 + ty * 4 + k) * 8000 + c0 + tx];
  __syncthreads();
#pragma unroll
  for (int k = 0; k < 4; ++k)
    outT[(long)(c0 + ty * 4 + k) * 256 + h0 + tx] = tile[tx][ty * 4 + k];
}

// ---------------- pad cls_W1/dl_W1 [256,272] -> [256,288] (zeros) ----------------
__global__ __launch_bounds__(256) void pad_w1(const float* __restrict__ w1,
                                              const float* __restrict__ w1d,
                                              float* __restrict__ o1,
                                              float* __restrict__ o2) {
  int idx = blockIdx.x * 256 + threadIdx.x;
  if (idx >= 2 * 256 * 288) return;
  int half = idx / (256 * 288);
  int r = idx % (256 * 288);
  int n = r / 288, k = r % 288;
  float v = (k < 272) ? (half ? w1d[n * 272 + k] : w1[n * 272 + k]) : 0.f;
  if (half) o2[r] = v; else o1[r] = v;
}

// ---------------- sparse embed: emb[bt,h] = b[h] + sum_c x!=0 * Wt[c,h] ----------------
__global__ __launch_bounds__(256) void embed_sparse(const float* __restrict__ x,
                                                    const float* __restrict__ Wt,
                                                    const float* __restrict__ eb,
                                                    float* __restrict__ emb) {
  __shared__ int sidx[512];
  __shared__ float sval[512];
  __shared__ int scnt;
  const int bt = blockIdx.x;  // 0..8191
  const int tid = threadIdx.x;
  if (tid == 0) scnt = 0;
  __syncthreads();
  const float* xr = x + (long)bt * 8000;
  for (int i = tid; i < 2000; i += 256) {
    float4 v = ((const float4*)xr)[i];
    if (v.x != 0.f) { int p = atomicAdd(&scnt, 1); if (p < 512) { sidx[p] = i * 4 + 0; sval[p] = v.x; } }
    if (v.y != 0.f) { int p = atomicAdd(&scnt, 1); if (p < 512) { sidx[p] = i * 4 + 1; sval[p] = v.y; } }
    if (v.z != 0.f) { int p = atomicAdd(&scnt, 1); if (p < 512) { sidx[p] = i * 4 + 2; sval[p] = v.z; } }
    if (v.w != 0.f) { int p = atomicAdd(&scnt, 1); if (p < 512) { sidx[p] = i * 4 + 3; sval[p] = v.w; } }
  }
  __syncthreads();
  const int n = min(scnt, 512);
  float acc = eb[tid];
  for (int i = 0; i < n; ++i) acc += sval[i] * Wt[(long)sidx[i] * 256 + tid];
  emb[(long)bt * 256 + tid] = acc;
}

// ---------------- generic GEMM: C[M,N] = act(A[M,K] @ B[N,K]^T + bias) ----------------
// bf16 MFMA 16x16x32, 64x64 tile, 4 waves. M,N mult of 64; K mult of 32.
__global__ __launch_bounds__(256) void gemm_bt(const float* __restrict__ A,
                                               const float* __restrict__ B,
                                               const float* __restrict__ bias,
                                               float* __restrict__ C,
                                               int M, int N, int K, int ldc, int act) {
  __shared__ short As[64][40];
  __shared__ short Bs[64][40];
  const int tid = threadIdx.x;
  const int lane = tid & 63, wave = tid >> 6;
  const int wm = wave >> 1, wn = wave & 1;
  const int l15 = lane & 15, lhi = lane >> 4;
  const int m0 = blockIdx.y * 64, n0 = blockIdx.x * 64;
  const int srow = tid >> 2, scol = (tid & 3) * 8;
  f32x4 acc[2][2];
#pragma unroll
  for (int i = 0; i < 2; ++i)
#pragma unroll
    for (int j = 0; j < 2; ++j) acc[i][j] = (f32x4){0.f, 0.f, 0.f, 0.f};

  for (int k0 = 0; k0 < K; k0 += 32) {
    __syncthreads();
    {
      const float* p = A + (long)(m0 + srow) * K + k0 + scol;
      float4 f0 = *(const float4*)p;
      float4 f1 = *(const float4*)(p + 4);
      short8 v;
      v[0] = f2bf(f0.x); v[1] = f2bf(f0.y); v[2] = f2bf(f0.z); v[3] = f2bf(f0.w);
      v[4] = f2bf(f1.x); v[5] = f2bf(f1.y); v[6] = f2bf(f1.z); v[7] = f2bf(f1.w);
      *(short8*)&As[srow][scol] = v;
      const float* q = B + (long)(n0 + srow) * K + k0 + scol;
      float4 g0 = *(const float4*)q;
      float4 g1 = *(const float4*)(q + 4);
      short8 u;
      u[0] = f2bf(g0.x); u[1] = f2bf(g0.y); u[2] = f2bf(g0.z); u[3] = f2bf(g0.w);
      u[4] = f2bf(g1.x); u[5] = f2bf(g1.y); u[6] = f2bf(g1.z); u[7] = f2bf(g1.w);
      *(short8*)&Bs[srow][scol] = u;
    }
    __syncthreads();
    short8 af0 = *(const short8*)&As[wm * 32 + l15][lhi * 8];
    short8 af1 = *(const short8*)&As[wm * 32 + 16 + l15][lhi * 8];
    short8 bf0 = *(const short8*)&Bs[wn * 32 + l15][lhi * 8];
    short8 bf1 = *(const short8*)&Bs[wn * 32 + 16 + l15][lhi * 8];
    acc[0][0] = __builtin_amdgcn_mfma_f32_16x16x32_bf16(af0, bf0, acc[0][0], 0, 0, 0);
    acc[0][1] = __builtin_amdgcn_mfma_f32_16x16x32_bf16(af0, bf1, acc[0][1], 0, 0, 0);
    acc[1][0] = __builtin_amdgcn_mfma_f32_16x16x32_bf16(af1, bf0, acc[1][0], 0, 0, 0);
    acc[1][1] = __builtin_amdgcn_mfma_f32_16x16x32_bf16(af1, bf1, acc[1][1], 0, 0, 0);
  }
#pragma unroll
  for (int j = 0; j < 2; ++j) {
    const int col = n0 + wn * 32 + j * 16 + l15;
    const float bv = bias[col];
#pragma unroll
    for (int i = 0; i < 2; ++i) {
#pragma unroll
      for (int r = 0; r < 4; ++r) {
        const int row = m0 + wm * 32 + i * 16 + lhi * 4 + r;
        float v = acc[i][j][r] + bv;
        if (act == 1) v = fmaxf(v, 0.f);
        else if (act == 2) v = tanh_fast(v);
        C[(long)row * ldc + col] = v;
      }
    }
  }
}

// ---------------- GRU scan v6: 1024 threads, 16 waves ----------------
// block = (gru, chunk of 16 batches). Wave w owns h-cols [w*16, w*16+16) for ALL
// 3 gates (tiles at gate-rows e*256 + w*16) -> weights = 96 regs/lane total;
// kt 0..5 in registers (72 regs), kt 6..7 in LDS (96KB). Everything fits <128
// VGPR at 16 waves/CU (4/SIMD) -- no spill, good latency hiding. Elementwise is
// thread-local (each thread holds r,z,n for its col/batches). xp staged via
// global_load_lds (single buffer); __syncthreads provides the vmcnt drain.
__global__ __launch_bounds__(1024, 4)
void gru_scan(const float* __restrict__ xpa,
              const float* __restrict__ xpb,
              const float* __restrict__ aWhh,
              const float* __restrict__ bWhh,
              const float* __restrict__ abhh,
              const float* __restrict__ bbhh,
              float* __restrict__ aout,
              float* __restrict__ bout) {
  const int tid = threadIdx.x;
  const int lane = tid & 63, w = tid >> 6;   // wave 0..15
  const int l15 = lane & 15, lhi = lane >> 4;
  const int gru = blockIdx.x >> 3, chunk = blockIdx.x & 7;
  const int b0 = chunk * 16;
  const float* xp  = gru ? xpb : xpa;
  const float* Whh = gru ? bWhh : aWhh;
  const float* bhh = gru ? bbhh : abhh;
  float* outp = gru ? bout : aout;

  __shared__ short hl[16][264];            // bf16 h, padded stride
  __shared__ float xpl[16][772];           // xp slice (row-padded; gld segs contiguous)
  __shared__ short wlds[2][16][3][64][8];  // kt=6,7 weight fragments

  // weights: wave w, gate e -> tile at gate-rows e*256 + w*16; lane holds
  // W[g = e*256 + w*16 + l15, kt*32 + lhi*8 + {0..7}]
  short8 wf[3][6];
#pragma unroll
  for (int e = 0; e < 3; ++e) {
    const int g = e * 256 + w * 16 + l15;
#pragma unroll
    for (int kt = 0; kt < 8; ++kt) {
      const float* p = Whh + (long)g * 256 + kt * 32 + lhi * 8;
      float4 f0 = *(const float4*)p;
      float4 f1 = *(const float4*)(p + 4);
      short8 v;
      v[0] = f2bf(f0.x); v[1] = f2bf(f0.y); v[2] = f2bf(f0.z); v[3] = f2bf(f0.w);
      v[4] = f2bf(f1.x); v[5] = f2bf(f1.y); v[6] = f2bf(f1.z); v[7] = f2bf(f1.w);
      if (kt < 6) wf[e][kt] = v;
      else *(short8*)&wlds[kt - 6][w][e][lane][0] = v;
    }
  }
  float bh[3];
#pragma unroll
  for (int e = 0; e < 3; ++e) bh[e] = bhh[e * 256 + w * 16 + l15];

  for (int i = tid; i < 16 * 264; i += 1024) (&hl[0][0])[i] = 0;

  // stage xp[t=0]: wave w stages batch-row w (768 floats = 3 segs of 256)
#pragma unroll
  for (int seg = 0; seg < 3; ++seg) {
    const float* gp = xp + ((long)(b0 + w) * 64 + 0) * 768 + seg * 256 + lane * 4;
    __builtin_amdgcn_global_load_lds((const __attribute__((address_space(1))) unsigned int*)gp,
                                     (__attribute__((address_space(3))) unsigned int*)&xpl[w][seg * 256],
                                     16, 0, 0);
  }
  __syncthreads();  // drains vmcnt: xpl[0] ready; hl/wlds visible

  float hreg[4] = {0.f, 0.f, 0.f, 0.f};  // h state: col=w*16+l15, batch=lhi*4+j

  for (int t = 0; t < 64; ++t) {
    // MFMA: hp[e] for 16 batches x 16 cols, K=256 (xp for t already in xpl)
    f32x4 acc[3];
#pragma unroll
    for (int e = 0; e < 3; ++e) acc[e] = (f32x4){0.f, 0.f, 0.f, 0.f};
#pragma unroll
    for (int kt = 0; kt < 6; ++kt) {
      short8 a = *(const short8*)&hl[l15][kt * 32 + lhi * 8];
      acc[0] = __builtin_amdgcn_mfma_f32_16x16x32_bf16(a, wf[0][kt], acc[0], 0, 0, 0);
      acc[1] = __builtin_amdgcn_mfma_f32_16x16x32_bf16(a, wf[1][kt], acc[1], 0, 0, 0);
      acc[2] = __builtin_amdgcn_mfma_f32_16x16x32_bf16(a, wf[2][kt], acc[2], 0, 0, 0);
    }
#pragma unroll
    for (int kt = 6; kt < 8; ++kt) {
      short8 a = *(const short8*)&hl[l15][kt * 32 + lhi * 8];
#pragma unroll
      for (int e = 0; e < 3; ++e) {
        short8 wl = *(const short8*)&wlds[kt - 6][w][e][lane][0];
        acc[e] = __builtin_amdgcn_mfma_f32_16x16x32_bf16(a, wl, acc[e], 0, 0, 0);
      }
    }
    __syncthreads();  // vmcnt(0): xpl[t] landed; all hl reads complete

    // elementwise GRU update (thread-local gates)
    const int col = w * 16 + l15;
#pragma unroll
    for (int j = 0; j < 4; ++j) {
      const int bl = lhi * 4 + j;
      const float r = sigf(xpl[bl][col] + acc[0][j] + bh[0]);
      const float z = sigf(xpl[bl][256 + col] + acc[1][j] + bh[1]);
      const float n = tanh_fast(xpl[bl][512 + col] + r * (acc[2][j] + bh[2]));
      const float hn = (1.f - z) * n + z * hreg[j];
      hreg[j] = hn;
      hl[bl][col] = f2bf(hn);
      outp[((long)(b0 + bl) * 64 + t) * 256 + col] = hn;
    }
    // hl writes visible; xpl consumed -> safe to restage
    asm volatile("s_waitcnt lgkmcnt(0)" ::: "memory");
    __builtin_amdgcn_s_barrier();
    __builtin_amdgcn_sched_barrier(0);
    if (t + 1 < 64) {  // issue next step's xp loads; land during next MFMA phase
#pragma unroll
      for (int seg = 0; seg < 3; ++seg) {
        const float* gp = xp + ((long)(b0 + w) * 64 + (t + 1)) * 768 + seg * 256 + lane * 4;
        __builtin_amdgcn_global_load_lds((const __attribute__((address_space(1))) unsigned int*)gp,
                                         (__attribute__((address_space(3))) unsigned int*)&xpl[w][seg * 256],
                                         16, 0, 0);
      }
    }
  }
}

// ---------------- e_alpha + softmax over T ----------------
__global__ __launch_bounds__(256) void alpha_softmax(const float* __restrict__ aout,
                                                     const float* __restrict__ aW,
                                                     const float* __restrict__ ab,
                                                     float* __restrict__ alpha) {
  __shared__ float part[64][4];
  const int b = blockIdx.x, tid = threadIdx.x;
  const int t = tid >> 2, q = tid & 3;
  const float* p = aout + (long)(b * 64 + t) * 256 + q * 64;
  const float* wv = aW + q * 64;
  float s = 0.f;
  for (int i = 0; i < 64; ++i) s += p[i] * wv[i];
  part[t][q] = s;
  __syncthreads();
  if (tid < 64) {
    float e = part[tid][0] + part[tid][1] + part[tid][2] + part[tid][3] + ab[0];
    float m = e;
    for (int k = 32; k; k >>= 1) m = fmaxf(m, __shfl_xor(m, k));
    float ex = __expf(e - m);
    float sum = ex;
    for (int k = 32; k; k >>= 1) sum += __shfl_xor(sum, k);
    alpha[b * 64 + tid] = ex / sum;
  }
}

// ---------------- context + combined[B,288] (context|demo|zero-pad) ----------------
__global__ __launch_bounds__(256) void context_combined(const float* __restrict__ alpha,
                                                        const float* __restrict__ emb,
                                                        const float* __restrict__ beta,
                                                        const float* __restrict__ demo,
                                                        float* __restrict__ comb) {
  const int b = blockIdx.x, h = threadIdx.x;
  float acc = 0.f;
  for (int t = 0; t < 64; ++t) {
    const float a = alpha[b * 64 + t];
    const long ix = (long)(b * 64 + t) * 256 + h;
    acc += a * emb[ix] * beta[ix];
  }
  comb[b * 288 + h] = acc;
  if (h < 16) comb[b * 288 + 256 + h] = demo[b * 16 + h];
  else if (h < 32) comb[b * 288 + 256 + h] = 0.f;
}

// ---------------- death/LOS head final dot ----------------
__global__ __launch_bounds__(64) void dl_head(const float* __restrict__ h2,
                                              const float* __restrict__ w,
                                              const float* __restrict__ bias,
                                              float* __restrict__ out) {
  const int b = blockIdx.x, lane = threadIdx.x;
  float s = 0.f;
#pragma unroll
  for (int i = 0; i < 4; ++i) s += h2[b * 256 + lane * 4 + i] * w[lane * 4 + i];
  for (int k = 32; k; k >>= 1) s += __shfl_xor(s, k);
  if (lane == 0) out[(long)b * 8001 + 8000] = s + bias[0];
}

extern "C" void kernel_launch(void* const* d_in, const int* in_sizes, int n_in,
                              void* d_out, int out_size, void* d_ws, size_t ws_size,
                              hipStream_t stream) {
  (void)in_sizes; (void)n_in; (void)out_size; (void)ws_size;
  const float* x      = (const float*)d_in[0];
  const float* demo   = (const float*)d_in[1];
  const float* embW   = (const float*)d_in[2];
  const float* embB   = (const float*)d_in[3];
  const float* aWih   = (const float*)d_in[4];
  const float* aWhh   = (const float*)d_in[5];
  const float* abih   = (const float*)d_in[6];
  const float* abhh   = (const float*)d_in[7];
  const float* bWih   = (const float*)d_in[8];
  const float* bWhh   = (const float*)d_in[9];
  const float* bbih   = (const float*)d_in[10];
  const float* bbhh   = (const float*)d_in[11];
  const float* attnAW = (const float*)d_in[12];
  const float* attnAb = (const float*)d_in[13];
  const float* attnBW = (const float*)d_in[14];
  const float* attnBb = (const float*)d_in[15];
  const float* clsW1  = (const float*)d_in[16];
  const float* clsb1  = (const float*)d_in[17];
  const float* clsW2  = (const float*)d_in[18];
  const float* clsb2  = (const float*)d_in[19];
  const float* dlW1   = (const float*)d_in[20];
  const float* dlb1   = (const float*)d_in[21];
  const float* dlW2   = (const float*)d_in[22];
  const float* dlb2   = (const float*)d_in[23];
  float* out = (float*)d_out;
  float* ws = (float*)d_ws;

  float* Wt    = ws;               // 8000*256     = 2,048,000
  float* emb   = Wt + 2048000;     // 8192*256     = 2,097,152
  float* xpa   = emb + 2097152;    // 8192*768     = 6,291,456
  float* xpb   = xpa + 6291456;    // 6,291,456
  float* aoutB = xpb + 6291456;    // 2,097,152
  float* boutB = aoutB + 2097152;  // 2,097,152
  float* betaB = boutB + 2097152;  // 2,097,152
  float* alpha = betaB + 2097152;  // 8,192
  float* comb  = alpha + 8192;     // 128*288 = 36,864
  float* h1    = comb + 36864;     // 32,768
  float* h2    = h1 + 32768;       // 32,768
  float* W1p   = h2 + 32768;       // 73,728
  float* W1pd  = W1p + 73728;      // 73,728  (total ~93.1 MB)

  transpose_w<<<dim3(250, 8), dim3(32, 8), 0, stream>>>(embW, Wt);
  pad_w1<<<dim3(576), dim3(256), 0, stream>>>(clsW1, dlW1, W1p, W1pd);
  embed_sparse<<<dim3(8192), dim3(256), 0, stream>>>(x, Wt, embB, emb);
  gemm_bt<<<dim3(12, 128), dim3(256), 0, stream>>>(emb, aWih, abih, xpa, 8192, 768, 256, 768, 0);
  gemm_bt<<<dim3(12, 128), dim3(256), 0, stream>>>(emb, bWih, bbih, xpb, 8192, 768, 256, 768, 0);
  gru_scan<<<dim3(16), dim3(1024), 0, stream>>>(xpa, xpb, aWhh, bWhh, abhh, bbhh, aoutB, boutB);
  alpha_softmax<<<dim3(128), dim3(256), 0, stream>>>(aoutB, attnAW, attnAb, alpha);
  gemm_bt<<<dim3(4, 128), dim3(256), 0, stream>>>(boutB, attnBW, attnBb, betaB, 8192, 256, 256, 256, 2);
  context_combined<<<dim3(128), dim3(256), 0, stream>>>(alpha, emb, betaB, demo, comb);
  gemm_bt<<<dim3(4, 2), dim3(256), 0, stream>>>(comb, W1p, clsb1, h1, 128, 256, 288, 256, 1);
  gemm_bt<<<dim3(4, 2), dim3(256), 0, stream>>>(comb, W1pd, dlb1, h2, 128, 256, 288, 256, 1);
  gemm_bt<<<dim3(125, 2), dim3(256), 0, stream>>>(h1, clsW2, clsb2, out, 128, 8000, 256, 8001, 0);
  dl_head<<<dim3(128), dim3(64), 0, stream>>>(h2, dlW2, dlb2, out);
}

// Round 7
// 413.595 us; speedup vs baseline: 1.8189x; 1.0064x over previous
//
#include <hip/hip_runtime.h>

// RETAIN forward. B=128 T=64 C=8000 H=256 D=16 G=768. All fp32 in/out;
// bf16 MFMA for matmuls, fp32 everywhere else.

typedef __attribute__((ext_vector_type(4))) float f32x4;
typedef __attribute__((ext_vector_type(8))) short short8;

__device__ inline short f2bf(float f) {
  unsigned u = __float_as_uint(f);
  u += 0x7fffu + ((u >> 16) & 1u);
  return (short)(u >> 16);
}
__device__ inline float sigf(float x) { return 1.f / (1.f + __expf(-x)); }
__device__ inline float tanh_fast(float x) {
  x = fminf(fmaxf(x, -15.f), 15.f);
  float e = __expf(2.f * x);
  return (e - 1.f) / (e + 1.f);
}

// ---------------- transpose embed_W [256,8000] -> Wt [8000,256] ----------------
__global__ void transpose_w(const float* __restrict__ in, float* __restrict__ outT) {
  __shared__ float tile[32][33];
  const int tx = threadIdx.x, ty = threadIdx.y;
  const int c0 = blockIdx.x * 32, h0 = blockIdx.y * 32;
#pragma unroll
  for (int k = 0; k < 4; ++k)
    tile[ty * 4 + k][tx] = in[(long)(h0 + ty * 4 + k) * 8000 + c0 + tx];
  __syncthreads();
#pragma unroll
  for (int k = 0; k < 4; ++k)
    outT[(long)(c0 + ty * 4 + k) * 256 + h0 + tx] = tile[tx][ty * 4 + k];
}

// ---------------- pad cls_W1/dl_W1 [256,272] -> [256,288] (zeros) ----------------
__global__ __launch_bounds__(256) void pad_w1(const float* __restrict__ w1,
                                              const float* __restrict__ w1d,
                                              float* __restrict__ o1,
                                              float* __restrict__ o2) {
  int idx = blockIdx.x * 256 + threadIdx.x;
  if (idx >= 2 * 256 * 288) return;
  int half = idx / (256 * 288);
  int r = idx % (256 * 288);
  int n = r / 288, k = r % 288;
  float v = (k < 272) ? (half ? w1d[n * 272 + k] : w1[n * 272 + k]) : 0.f;
  if (half) o2[r] = v; else o1[r] = v;
}

// ---------------- sparse embed: emb[bt,h] = b[h] + sum_c x!=0 * Wt[c,h] ----------------
__global__ __launch_bounds__(256) void embed_sparse(const float* __restrict__ x,
                                                    const float* __restrict__ Wt,
                                                    const float* __restrict__ eb,
                                                    float* __restrict__ emb) {
  __shared__ int sidx[512];
  __shared__ float sval[512];
  __shared__ int scnt;
  const int bt = blockIdx.x;  // 0..8191
  const int tid = threadIdx.x;
  if (tid == 0) scnt = 0;
  __syncthreads();
  const float* xr = x + (long)bt * 8000;
  for (int i = tid; i < 2000; i += 256) {
    float4 v = ((const float4*)xr)[i];
    if (v.x != 0.f) { int p = atomicAdd(&scnt, 1); if (p < 512) { sidx[p] = i * 4 + 0; sval[p] = v.x; } }
    if (v.y != 0.f) { int p = atomicAdd(&scnt, 1); if (p < 512) { sidx[p] = i * 4 + 1; sval[p] = v.y; } }
    if (v.z != 0.f) { int p = atomicAdd(&scnt, 1); if (p < 512) { sidx[p] = i * 4 + 2; sval[p] = v.z; } }
    if (v.w != 0.f) { int p = atomicAdd(&scnt, 1); if (p < 512) { sidx[p] = i * 4 + 3; sval[p] = v.w; } }
  }
  __syncthreads();
  const int n = min(scnt, 512);
  float acc = eb[tid];
  for (int i = 0; i < n; ++i) acc += sval[i] * Wt[(long)sidx[i] * 256 + tid];
  emb[(long)bt * 256 + tid] = acc;
}

// ---------------- generic GEMM: C[M,N] = act(A[M,K] @ B[N,K]^T + bias) ----------------
// bf16 MFMA 16x16x32, 64x64 tile, 4 waves. M,N mult of 64; K mult of 32.
__global__ __launch_bounds__(256) void gemm_bt(const float* __restrict__ A,
                                               const float* __restrict__ B,
                                               const float* __restrict__ bias,
                                               float* __restrict__ C,
                                               int M, int N, int K, int ldc, int act) {
  __shared__ short As[64][40];
  __shared__ short Bs[64][40];
  const int tid = threadIdx.x;
  const int lane = tid & 63, wave = tid >> 6;
  const int wm = wave >> 1, wn = wave & 1;
  const int l15 = lane & 15, lhi = lane >> 4;
  const int m0 = blockIdx.y * 64, n0 = blockIdx.x * 64;
  const int srow = tid >> 2, scol = (tid & 3) * 8;
  f32x4 acc[2][2];
#pragma unroll
  for (int i = 0; i < 2; ++i)
#pragma unroll
    for (int j = 0; j < 2; ++j) acc[i][j] = (f32x4){0.f, 0.f, 0.f, 0.f};

  for (int k0 = 0; k0 < K; k0 += 32) {
    __syncthreads();
    {
      const float* p = A + (long)(m0 + srow) * K + k0 + scol;
      float4 f0 = *(const float4*)p;
      float4 f1 = *(const float4*)(p + 4);
      short8 v;
      v[0] = f2bf(f0.x); v[1] = f2bf(f0.y); v[2] = f2bf(f0.z); v[3] = f2bf(f0.w);
      v[4] = f2bf(f1.x); v[5] = f2bf(f1.y); v[6] = f2bf(f1.z); v[7] = f2bf(f1.w);
      *(short8*)&As[srow][scol] = v;
      const float* q = B + (long)(n0 + srow) * K + k0 + scol;
      float4 g0 = *(const float4*)q;
      float4 g1 = *(const float4*)(q + 4);
      short8 u;
      u[0] = f2bf(g0.x); u[1] = f2bf(g0.y); u[2] = f2bf(g0.z); u[3] = f2bf(g0.w);
      u[4] = f2bf(g1.x); u[5] = f2bf(g1.y); u[6] = f2bf(g1.z); u[7] = f2bf(g1.w);
      *(short8*)&Bs[srow][scol] = u;
    }
    __syncthreads();
    short8 af0 = *(const short8*)&As[wm * 32 + l15][lhi * 8];
    short8 af1 = *(const short8*)&As[wm * 32 + 16 + l15][lhi * 8];
    short8 bf0 = *(const short8*)&Bs[wn * 32 + l15][lhi * 8];
    short8 bf1 = *(const short8*)&Bs[wn * 32 + 16 + l15][lhi * 8];
    acc[0][0] = __builtin_amdgcn_mfma_f32_16x16x32_bf16(af0, bf0, acc[0][0], 0, 0, 0);
    acc[0][1] = __builtin_amdgcn_mfma_f32_16x16x32_bf16(af0, bf1, acc[0][1], 0, 0, 0);
    acc[1][0] = __builtin_amdgcn_mfma_f32_16x16x32_bf16(af1, bf0, acc[1][0], 0, 0, 0);
    acc[1][1] = __builtin_amdgcn_mfma_f32_16x16x32_bf16(af1, bf1, acc[1][1], 0, 0, 0);
  }
#pragma unroll
  for (int j = 0; j < 2; ++j) {
    const int col = n0 + wn * 32 + j * 16 + l15;
    const float bv = bias[col];
#pragma unroll
    for (int i = 0; i < 2; ++i) {
#pragma unroll
      for (int r = 0; r < 4; ++r) {
        const int row = m0 + wm * 32 + i * 16 + lhi * 4 + r;
        float v = acc[i][j][r] + bv;
        if (act == 1) v = fmaxf(v, 0.f);
        else if (act == 2) v = tanh_fast(v);
        C[(long)row * ldc + col] = v;
      }
    }
  }
}

// ---------------- GRU scan v7: 64 blocks x 1024 threads, pinned 4 waves/EU ----------------
// block = (gru, chunk of 4 batches). Wave w owns h-cols [w*16, w*16+16) for ALL 3
// gates; weights kt 0..5 in regs (72), kt 6..7 in LDS (96KB). waves_per_eu(4,4)
// pins the allocator at the 128-reg budget (R6's launch_bounds(1024,4) let it
// target 8 waves/EU=64 regs and spill the weights). 64 blocks spread the xp
// stream over 4x the CUs. Elementwise masked to lhi==0 (batches 0..3).
__global__ __attribute__((amdgpu_flat_work_group_size(1024, 1024), amdgpu_waves_per_eu(4, 4)))
void gru_scan(const float* __restrict__ xpa,
              const float* __restrict__ xpb,
              const float* __restrict__ aWhh,
              const float* __restrict__ bWhh,
              const float* __restrict__ abhh,
              const float* __restrict__ bbhh,
              float* __restrict__ aout,
              float* __restrict__ bout) {
  const int tid = threadIdx.x;
  const int lane = tid & 63, w = tid >> 6;   // wave 0..15
  const int l15 = lane & 15, lhi = lane >> 4;
  const int gru = blockIdx.x >> 5, chunk = blockIdx.x & 31;
  const int b0 = chunk * 4;
  const float* xp  = gru ? xpb : xpa;
  const float* Whh = gru ? bWhh : aWhh;
  const float* bhh = gru ? bbhh : abhh;
  float* outp = gru ? bout : aout;

  __shared__ short hl[16][264];            // bf16 h (rows 4..15 stay zero)
  __shared__ float xpl[4][768];            // xp slice, contiguous (gld dest)
  __shared__ short wlds[2][16][3][64][8];  // kt=6,7 weight fragments

  // weights: wave w, gate e -> tile at gate-rows e*256 + w*16; lane holds
  // W[g = e*256 + w*16 + l15, kt*32 + lhi*8 + {0..7}]
  short8 wf[3][6];
#pragma unroll
  for (int e = 0; e < 3; ++e) {
    const int g = e * 256 + w * 16 + l15;
#pragma unroll
    for (int kt = 0; kt < 8; ++kt) {
      const float* p = Whh + (long)g * 256 + kt * 32 + lhi * 8;
      float4 f0 = *(const float4*)p;
      float4 f1 = *(const float4*)(p + 4);
      short8 v;
      v[0] = f2bf(f0.x); v[1] = f2bf(f0.y); v[2] = f2bf(f0.z); v[3] = f2bf(f0.w);
      v[4] = f2bf(f1.x); v[5] = f2bf(f1.y); v[6] = f2bf(f1.z); v[7] = f2bf(f1.w);
      if (kt < 6) wf[e][kt] = v;
      else *(short8*)&wlds[kt - 6][w][e][lane][0] = v;
    }
  }
  float bh[3];
#pragma unroll
  for (int e = 0; e < 3; ++e) bh[e] = bhh[e * 256 + w * 16 + l15];

  for (int i = tid; i < 16 * 264; i += 1024) (&hl[0][0])[i] = 0;

  // stage xp[t=0]: waves 0..11: row=w/3, seg=w%3 -> 1KB contiguous segment
  if (w < 12) {
    const int row = w / 3, seg = w % 3;
    const float* gp = xp + ((long)(b0 + row) * 64 + 0) * 768 + seg * 256 + lane * 4;
    __builtin_amdgcn_global_load_lds((const __attribute__((address_space(1))) unsigned int*)gp,
                                     (__attribute__((address_space(3))) unsigned int*)&xpl[row][seg * 256],
                                     16, 0, 0);
  }
  __syncthreads();  // drains vmcnt: xpl[0] ready; hl/wlds visible

  float hreg[4] = {0.f, 0.f, 0.f, 0.f};  // h state (lhi==0): col=w*16+l15, batch=j
  const int col = w * 16 + l15;
  // hoisted output pointers (valid for lhi==0 lanes; advanced by 256 per step)
  float* op[4];
#pragma unroll
  for (int j = 0; j < 4; ++j) op[j] = outp + ((long)(b0 + j) * 64 + 0) * 256 + col;

  for (int t = 0; t < 64; ++t) {
    // MFMA: hp[e] for 16 cols, K=256
    f32x4 acc[3];
#pragma unroll
    for (int e = 0; e < 3; ++e) acc[e] = (f32x4){0.f, 0.f, 0.f, 0.f};
#pragma unroll
    for (int kt = 0; kt < 6; ++kt) {
      short8 a = *(const short8*)&hl[l15][kt * 32 + lhi * 8];
      acc[0] = __builtin_amdgcn_mfma_f32_16x16x32_bf16(a, wf[0][kt], acc[0], 0, 0, 0);
      acc[1] = __builtin_amdgcn_mfma_f32_16x16x32_bf16(a, wf[1][kt], acc[1], 0, 0, 0);
      acc[2] = __builtin_amdgcn_mfma_f32_16x16x32_bf16(a, wf[2][kt], acc[2], 0, 0, 0);
    }
#pragma unroll
    for (int kt = 6; kt < 8; ++kt) {
      short8 a = *(const short8*)&hl[l15][kt * 32 + lhi * 8];
#pragma unroll
      for (int e = 0; e < 3; ++e) {
        short8 wl = *(const short8*)&wlds[kt - 6][w][e][lane][0];
        acc[e] = __builtin_amdgcn_mfma_f32_16x16x32_bf16(a, wl, acc[e], 0, 0, 0);
      }
    }
    __syncthreads();  // vmcnt(0): xpl[t] landed; all hl reads complete

    // elementwise GRU update: only lhi==0 lanes hold valid rows (batches 0..3)
    if (lhi == 0) {
#pragma unroll
      for (int j = 0; j < 4; ++j) {
        const float r = sigf(xpl[j][col] + acc[0][j] + bh[0]);
        const float z = sigf(xpl[j][256 + col] + acc[1][j] + bh[1]);
        const float n = tanh_fast(xpl[j][512 + col] + r * (acc[2][j] + bh[2]));
        const float hn = (1.f - z) * n + z * hreg[j];
        hreg[j] = hn;
        hl[j][col] = f2bf(hn);
        *op[j] = hn;
        op[j] += 256;
      }
    }
    // hl writes visible; xpl consumed -> safe to restage
    asm volatile("s_waitcnt lgkmcnt(0)" ::: "memory");
    __builtin_amdgcn_s_barrier();
    __builtin_amdgcn_sched_barrier(0);
    if (t + 1 < 64 && w < 12) {  // issue next step's xp loads
      const int row = w / 3, seg = w % 3;
      const float* gp = xp + ((long)(b0 + row) * 64 + (t + 1)) * 768 + seg * 256 + lane * 4;
      __builtin_amdgcn_global_load_lds((const __attribute__((address_space(1))) unsigned int*)gp,
                                       (__attribute__((address_space(3))) unsigned int*)&xpl[row][seg * 256],
                                       16, 0, 0);
    }
  }
}

// ---------------- e_alpha + softmax over T ----------------
__global__ __launch_bounds__(256) void alpha_softmax(const float* __restrict__ aout,
                                                     const float* __restrict__ aW,
                                                     const float* __restrict__ ab,
                                                     float* __restrict__ alpha) {
  __shared__ float part[64][4];
  const int b = blockIdx.x, tid = threadIdx.x;
  const int t = tid >> 2, q = tid & 3;
  const float* p = aout + (long)(b * 64 + t) * 256 + q * 64;
  const float* wv = aW + q * 64;
  float s = 0.f;
  for (int i = 0; i < 64; ++i) s += p[i] * wv[i];
  part[t][q] = s;
  __syncthreads();
  if (tid < 64) {
    float e = part[tid][0] + part[tid][1] + part[tid][2] + part[tid][3] + ab[0];
    float m = e;
    for (int k = 32; k; k >>= 1) m = fmaxf(m, __shfl_xor(m, k));
    float ex = __expf(e - m);
    float sum = ex;
    for (int k = 32; k; k >>= 1) sum += __shfl_xor(sum, k);
    alpha[b * 64 + tid] = ex / sum;
  }
}

// ---------------- context + combined[B,288] (context|demo|zero-pad) ----------------
__global__ __launch_bounds__(256) void context_combined(const float* __restrict__ alpha,
                                                        const float* __restrict__ emb,
                                                        const float* __restrict__ beta,
                                                        const float* __restrict__ demo,
                                                        float* __restrict__ comb) {
  const int b = blockIdx.x, h = threadIdx.x;
  float acc = 0.f;
  for (int t = 0; t < 64; ++t) {
    const float a = alpha[b * 64 + t];
    const long ix = (long)(b * 64 + t) * 256 + h;
    acc += a * emb[ix] * beta[ix];
  }
  comb[b * 288 + h] = acc;
  if (h < 16) comb[b * 288 + 256 + h] = demo[b * 16 + h];
  else if (h < 32) comb[b * 288 + 256 + h] = 0.f;
}

// ---------------- death/LOS head final dot ----------------
__global__ __launch_bounds__(64) void dl_head(const float* __restrict__ h2,
                                              const float* __restrict__ w,
                                              const float* __restrict__ bias,
                                              float* __restrict__ out) {
  const int b = blockIdx.x, lane = threadIdx.x;
  float s = 0.f;
#pragma unroll
  for (int i = 0; i < 4; ++i) s += h2[b * 256 + lane * 4 + i] * w[lane * 4 + i];
  for (int k = 32; k; k >>= 1) s += __shfl_xor(s, k);
  if (lane == 0) out[(long)b * 8001 + 8000] = s + bias[0];
}

extern "C" void kernel_launch(void* const* d_in, const int* in_sizes, int n_in,
                              void* d_out, int out_size, void* d_ws, size_t ws_size,
                              hipStream_t stream) {
  (void)in_sizes; (void)n_in; (void)out_size; (void)ws_size;
  const float* x      = (const float*)d_in[0];
  const float* demo   = (const float*)d_in[1];
  const float* embW   = (const float*)d_in[2];
  const float* embB   = (const float*)d_in[3];
  const float* aWih   = (const float*)d_in[4];
  const float* aWhh   = (const float*)d_in[5];
  const float* abih   = (const float*)d_in[6];
  const float* abhh   = (const float*)d_in[7];
  const float* bWih   = (const float*)d_in[8];
  const float* bWhh   = (const float*)d_in[9];
  const float* bbih   = (const float*)d_in[10];
  const float* bbhh   = (const float*)d_in[11];
  const float* attnAW = (const float*)d_in[12];
  const float* attnAb = (const float*)d_in[13];
  const float* attnBW = (const float*)d_in[14];
  const float* attnBb = (const float*)d_in[15];
  const float* clsW1  = (const float*)d_in[16];
  const float* clsb1  = (const float*)d_in[17];
  const float* clsW2  = (const float*)d_in[18];
  const float* clsb2  = (const float*)d_in[19];
  const float* dlW1   = (const float*)d_in[20];
  const float* dlb1   = (const float*)d_in[21];
  const float* dlW2   = (const float*)d_in[22];
  const float* dlb2   = (const float*)d_in[23];
  float* out = (float*)d_out;
  float* ws = (float*)d_ws;

  float* Wt    = ws;               // 8000*256     = 2,048,000
  float* emb   = Wt + 2048000;     // 8192*256     = 2,097,152
  float* xpa   = emb + 2097152;    // 8192*768     = 6,291,456
  float* xpb   = xpa + 6291456;    // 6,291,456
  float* aoutB = xpb + 6291456;    // 2,097,152
  float* boutB = aoutB + 2097152;  // 2,097,152
  float* betaB = boutB + 2097152;  // 2,097,152
  float* alpha = betaB + 2097152;  // 8,192
  float* comb  = alpha + 8192;     // 128*288 = 36,864
  float* h1    = comb + 36864;     // 32,768
  float* h2    = h1 + 32768;       // 32,768
  float* W1p   = h2 + 32768;       // 73,728
  float* W1pd  = W1p + 73728;      // 73,728  (total ~93.1 MB)

  transpose_w<<<dim3(250, 8), dim3(32, 8), 0, stream>>>(embW, Wt);
  pad_w1<<<dim3(576), dim3(256), 0, stream>>>(clsW1, dlW1, W1p, W1pd);
  embed_sparse<<<dim3(8192), dim3(256), 0, stream>>>(x, Wt, embB, emb);
  gemm_bt<<<dim3(12, 128), dim3(256), 0, stream>>>(emb, aWih, abih, xpa, 8192, 768, 256, 768, 0);
  gemm_bt<<<dim3(12, 128), dim3(256), 0, stream>>>(emb, bWih, bbih, xpb, 8192, 768, 256, 768, 0);
  gru_scan<<<dim3(64), dim3(1024), 0, stream>>>(xpa, xpb, aWhh, bWhh, abhh, bbhh, aoutB, boutB);
  alpha_softmax<<<dim3(128), dim3(256), 0, stream>>>(aoutB, attnAW, attnAb, alpha);
  gemm_bt<<<dim3(4, 128), dim3(256), 0, stream>>>(boutB, attnBW, attnBb, betaB, 8192, 256, 256, 256, 2);
  context_combined<<<dim3(128), dim3(256), 0, stream>>>(alpha, emb, betaB, demo, comb);
  gemm_bt<<<dim3(4, 2), dim3(256), 0, stream>>>(comb, W1p, clsb1, h1, 128, 256, 288, 256, 1);
  gemm_bt<<<dim3(4, 2), dim3(256), 0, stream>>>(comb, W1pd, dlb1, h2, 128, 256, 288, 256, 1);
  gemm_bt<<<dim3(125, 2), dim3(256), 0, stream>>>(h1, clsW2, clsb2, out, 128, 8000, 256, 8001, 0);
  dl_head<<<dim3(128), dim3(64), 0, stream>>>(h2, dlW2, dlb2, out);
}